// Round 13
// baseline (315.783 us; speedup 1.0000x reference)
//
#include <hip/hip_runtime.h>
#include <hip/hip_bf16.h>

// Causal attention head. B=8, T=4096, D_EMBED=128, HEAD=64. f32 wire, bf16 MFMA.
// Two dispatches: qkv (inlined vectorized W-transpose + zero-init) and attn
// (balanced split-k, LDS double-buffer w/ 1 barrier/iter, LLC-atomic combine).
typedef __attribute__((ext_vector_type(8))) short bf16x8;
typedef __attribute__((ext_vector_type(4))) short short4v;
typedef __attribute__((ext_vector_type(4))) float f32x4;

#define MFMA16(a, b, c) __builtin_amdgcn_mfma_f32_16x16x32_bf16((a), (b), (c), 0, 0, 0)

// K=16 MFMA: P's S^T C-layout == its A-frag layout -> PV straight from registers.
// Wrapped so the HOST pass (where __has_builtin is false) still parses: the
// stub branch is never executed on device (r9/r12 prove _1k exists on gfx950).
__device__ inline f32x4 mfmax16(short4v a, short4v b, f32x4 c) {
#if __has_builtin(__builtin_amdgcn_mfma_f32_16x16x16bf16_1k)
    return __builtin_amdgcn_mfma_f32_16x16x16bf16_1k(a, b, c, 0, 0, 0);
#else
    return c;   // host-pass stub only
#endif
}

constexpr int Bn = 8, Tn = 4096, Dn = 128, Hn = 64;

__device__ inline unsigned short f2b(float f) {
    union { float f; unsigned u; } v; v.f = f;
    unsigned r = v.u + 0x7fff + ((v.u >> 16) & 1);   // RNE, inputs finite
    return (unsigned short)(r >> 16);
}
#if __has_builtin(__builtin_amdgcn_cvt_pk_bf16_f32)
typedef __attribute__((ext_vector_type(2))) __bf16 bf16x2_t;
__device__ inline unsigned pk2(float a, float b) {
    union { bf16x2_t v; unsigned u; } c;
    c.v = __builtin_amdgcn_cvt_pk_bf16_f32(a, b);
    return c.u;
}
#else
__device__ inline unsigned pk2(float a, float b) {
    return (unsigned)f2b(a) | ((unsigned)f2b(b) << 16);
}
#endif
__device__ inline short4v pk4(float a, float b, float c, float d) {
    union { unsigned u[2]; short4v s; } r;
    r.u[0] = pk2(a, b); r.u[1] = pk2(c, d);
    return r.s;
}

// ---- Kernel 1: QKV projection; inlined vectorized W transpose; zero-inits. ----
__global__ __launch_bounds__(256) void qkv(const float* __restrict__ X,
                                           const float* __restrict__ Wq,
                                           const float* __restrict__ Wk,
                                           const float* __restrict__ Wv,
                                           unsigned short* __restrict__ Qp,
                                           unsigned short* __restrict__ Kp,
                                           unsigned short* __restrict__ VTp,
                                           float* __restrict__ Out,
                                           float* __restrict__ Lsum,
                                           int* __restrict__ cnt) {
    __shared__ unsigned short xt[64 * 136];   // X tile bf16
    __shared__ unsigned short wt[64 * 136];   // W^T tile bf16 (one mat at a time)
    __shared__ unsigned short ot[64 * 72];    // output staging
    int tid = threadIdx.x, w = tid >> 6, lane = tid & 63, quad = lane >> 4, l15 = lane & 15;
    int g = blockIdx.x;
    int m0 = g * 64;
    int b = m0 >> 12, tloc = m0 & (Tn - 1);
    const float kLog2Scale = 0.12751879523175464f;  // (1/sqrt(128)) * log2(e)

    // zero-init: Out (this block's 4096 f32), Lsum slice, counters
    #pragma unroll
    for (int i = 0; i < 4; i++)
        *(f32x4*)&Out[(size_t)g * 4096 + (size_t)(tid + i * 256) * 4] = (f32x4){0.f, 0.f, 0.f, 0.f};
    if (tid < 64) Lsum[g * 64 + tid] = 0.f;
    if (g == 0) { cnt[tid] = 0; cnt[tid + 256] = 0; }

    // stage X tile (coalesced f32x4 -> bf16)
    #pragma unroll
    for (int c = 0; c < 8; c++) {
        int e = tid * 4 + c * 1024;
        int row = e >> 7, col = e & 127;
        f32x4 v = *(const f32x4*)&X[(size_t)(m0 + row) * Dn + col];
        *(short4v*)&xt[row * 136 + col] = pk4(v[0], v[1], v[2], v[3]);
    }
    __syncthreads();

    bf16x8 a[4];
    #pragma unroll
    for (int kt = 0; kt < 4; kt++)
        a[kt] = *(const bf16x8*)&xt[(w * 16 + l15) * 136 + kt * 32 + quad * 8];

    for (int mat = 0; mat < 3; mat++) {
        const float* W = (mat == 0) ? Wq : (mat == 1) ? Wk : Wv;
        __syncthreads();   // prior mat's wt frag reads + ot copy-out done
        // vectorized transpose: W[k][n] f32 -> wt[n][k] bf16, b64 LDS writes
        #pragma unroll
        for (int p = 0; p < 2; p++) {
            int kb = (tid >> 4) * 4 + p * 64;     // 0..124 step 4
            int n4 = (tid & 15) * 4;
            f32x4 wv0 = *(const f32x4*)&W[(kb + 0) * Hn + n4];
            f32x4 wv1 = *(const f32x4*)&W[(kb + 1) * Hn + n4];
            f32x4 wv2 = *(const f32x4*)&W[(kb + 2) * Hn + n4];
            f32x4 wv3 = *(const f32x4*)&W[(kb + 3) * Hn + n4];
            #pragma unroll
            for (int n = 0; n < 4; n++)
                *(short4v*)&wt[(n4 + n) * 136 + kb] = pk4(wv0[n], wv1[n], wv2[n], wv3[n]);
        }
        __syncthreads();

        f32x4 acc[4];
        #pragma unroll
        for (int nt = 0; nt < 4; nt++) {
            acc[nt] = (f32x4){0.f, 0.f, 0.f, 0.f};
            const unsigned short* wtm = &wt[(nt * 16 + l15) * 136 + quad * 8];
            #pragma unroll
            for (int kt = 0; kt < 4; kt++)
                acc[nt] = MFMA16(a[kt], *(const bf16x8*)&wtm[kt * 32], acc[nt]);
        }
        __syncthreads();
        if (mat < 2) {
            float sc = (mat == 0) ? kLog2Scale : 1.0f;   // fold softmax scale into Q
            #pragma unroll
            for (int nt = 0; nt < 4; nt++)
                #pragma unroll
                for (int rg = 0; rg < 4; rg++)
                    ot[(w * 16 + quad * 4 + rg) * 72 + nt * 16 + l15] = f2b(acc[nt][rg] * sc);
        } else {
            #pragma unroll
            for (int nt = 0; nt < 4; nt++)
                *(short4v*)&ot[(nt * 16 + l15) * 72 + w * 16 + quad * 4] =
                    pk4(acc[nt][0], acc[nt][1], acc[nt][2], acc[nt][3]);
        }
        __syncthreads();
        if (mat < 2) {
            unsigned short* O = mat ? Kp : Qp;
            #pragma unroll
            for (int i = 0; i < 2; i++) {
                int row = (tid >> 3) + 32 * i, ch8 = tid & 7;
                *(bf16x8*)&O[(size_t)(m0 + row) * Hn + ch8 * 8] = *(const bf16x8*)&ot[row * 72 + ch8 * 8];
            }
        } else {
            #pragma unroll
            for (int i = 0; i < 2; i++) {
                int h = (tid >> 3) + 32 * i, ch8 = tid & 7;
                *(bf16x8*)&VTp[((size_t)(b * Hn + h)) * Tn + tloc + ch8 * 8] = *(const bf16x8*)&ot[h * 72 + ch8 * 8];
            }
        }
    }
}

// ---- Kernel 2: balanced split-k flash attention; LDS double-buffer (1 barrier
// per iteration); all-wave atomic combine; last-block normalize. ----
__global__ __launch_bounds__(256) void attn(const unsigned short* __restrict__ Qp,
                                            const unsigned short* __restrict__ Kp,
                                            const unsigned short* __restrict__ VTp,
                                            float* __restrict__ Out,
                                            float* __restrict__ Lsum,
                                            int* __restrict__ cnt) {
    __shared__ __align__(16) char shmem[2][18432];   // dbuf: Ks[64][72] + Vs[64][72] each
    __shared__ float Lbuf[2][64];
    __shared__ int lastflag;

    int idx = blockIdx.x;
    int b = idx & 7;
    int c = 159 - (idx >> 3);                        // big chunks dispatch first
    int qt, ch, nch;
    if (c < 16)      { qt = c;                 ch = 0;          nch = 1; }
    else if (c < 48) { int t = c - 16; qt = 16 + (t >> 1); ch = t & 1;      nch = 2; }
    else if (c < 96) { int t = c - 48; int q3 = t / 3; qt = 32 + q3; ch = t - 3 * q3; nch = 3; }
    else             { int t = c - 96; qt = 48 + (t >> 2); ch = t & 3;      nch = 4; }
    int k0 = ch * 16, k1 = min(qt, k0 + 15);

    int tid = threadIdx.x, w = tid >> 6, lane = tid & 63, quad = lane >> 4, l15 = lane & 15;
    int qh = w & 1, kh = w >> 1;
    int Q0 = qt * 64;
    const unsigned short* Kb = Kp + (size_t)b * Tn * Hn;
    const unsigned short* Vb = VTp + (size_t)b * Hn * Tn;

    int srow = tid >> 3, scol = (tid & 7) * 8;       // staging: 2 f32x4/thread/tile
    const f32x4* Ksrc = (const f32x4*)Kb;

    // tile k0 -> regs -> buf0 (loop-top barrier makes it visible)
    f32x4 kr[2], vr[2];
    #pragma unroll
    for (int i = 0; i < 2; i++) kr[i] = Ksrc[k0 * 512 + tid + i * 256];
    #pragma unroll
    for (int i = 0; i < 2; i++) vr[i] = *(const f32x4*)&Vb[(size_t)(srow + i * 32) * Tn + k0 * 64 + scol];
    {
        unsigned short* Ks0 = (unsigned short*)&shmem[0][0];
        unsigned short* Vs0 = Ks0 + 64 * 72;
        #pragma unroll
        for (int i = 0; i < 2; i++) *(f32x4*)&Ks0[(srow + i * 32) * 72 + scol] = kr[i];
        #pragma unroll
        for (int i = 0; i < 2; i++) *(f32x4*)&Vs0[(srow + i * 32) * 72 + scol] = vr[i];
    }

    bf16x8 qf[2][2];
    {
        const unsigned short* Qb = Qp + ((size_t)b * Tn + Q0 + qh * 32) * Hn;
        #pragma unroll
        for (int nq = 0; nq < 2; nq++)
            #pragma unroll
            for (int hc = 0; hc < 2; hc++)
                qf[nq][hc] = *(const bf16x8*)&Qb[(nq * 16 + l15) * Hn + hc * 32 + quad * 8];
    }

    f32x4 o[2][4];
    #pragma unroll
    for (int nq = 0; nq < 2; nq++)
        #pragma unroll
        for (int nh = 0; nh < 4; nh++) o[nq][nh] = (f32x4){0.f, 0.f, 0.f, 0.f};
    float li[2] = {0.f, 0.f};

    int cur = 0;
    for (int kt = k0; kt <= k1; kt++) {
        __syncthreads();   // buf[cur] writes visible; prior reads of buf[cur^1] done
        bool pref = (kt < k1);
        if (pref) {        // issue next tile's loads; latency overlaps compute
            #pragma unroll
            for (int i = 0; i < 2; i++) kr[i] = Ksrc[(kt + 1) * 512 + tid + i * 256];
            #pragma unroll
            for (int i = 0; i < 2; i++)
                vr[i] = *(const f32x4*)&Vb[(size_t)(srow + i * 32) * Tn + (kt + 1) * 64 + scol];
        }
        unsigned short* Ks = (unsigned short*)&shmem[cur][0];
        unsigned short* Vs = Ks + 64 * 72;

        bf16x8 kf[2][2];
        #pragma unroll
        for (int mt = 0; mt < 2; mt++)
            #pragma unroll
            for (int hc = 0; hc < 2; hc++)
                kf[mt][hc] = *(const bf16x8*)&Ks[(kh * 32 + mt * 16 + l15) * 72 + hc * 32 + quad * 8];

        // S^T tiles: rows k' = mt*16+quad*4+rg, cols q = nq*16+l15 (log2-scaled)
        f32x4 s[2][2];
        #pragma unroll
        for (int mt = 0; mt < 2; mt++)
            #pragma unroll
            for (int nq = 0; nq < 2; nq++) {
                f32x4 acc = {0.f, 0.f, 0.f, 0.f};
                acc = MFMA16(kf[mt][0], qf[nq][0], acc);
                acc = MFMA16(kf[mt][1], qf[nq][1], acc);
                s[mt][nq] = acc;
            }

        bool diag = (kt == qt);
        int kbase = kt * 64 + kh * 32 + quad * 4;
        int qbase = Q0 + qh * 32 + l15;

        short4v vB[2][4];
        #pragma unroll
        for (int mt = 0; mt < 2; mt++)
            #pragma unroll
            for (int nh = 0; nh < 4; nh++)
                vB[mt][nh] = *(const short4v*)&Vs[(nh * 16 + l15) * 72 + kh * 32 + mt * 16 + quad * 4];
        short4v pkv[2][2];
        #pragma unroll
        for (int mt = 0; mt < 2; mt++) {
            #pragma unroll
            for (int nq = 0; nq < 2; nq++) {
                float p[4];
                #pragma unroll
                for (int rg = 0; rg < 4; rg++) {
                    float pe = __builtin_amdgcn_exp2f(s[mt][nq][rg]);
                    if (diag && (kbase + mt * 16 + rg > qbase + nq * 16)) pe = 0.f;
                    li[nq] += pe;
                    p[rg] = pe;
                }
                pkv[mt][nq] = pk4(p[0], p[1], p[2], p[3]);
            }
        }
        #pragma unroll
        for (int mt = 0; mt < 2; mt++)
            #pragma unroll
            for (int nq = 0; nq < 2; nq++)
                #pragma unroll
                for (int nh = 0; nh < 4; nh++)
                    o[nq][nh] = mfmax16(pkv[mt][nq], vB[mt][nh], o[nq][nh]);

        if (pref) {        // stage tile kt+1 into the alternate buffer
            unsigned short* Ksn = (unsigned short*)&shmem[cur ^ 1][0];
            unsigned short* Vsn = Ksn + 64 * 72;
            #pragma unroll
            for (int i = 0; i < 2; i++) *(f32x4*)&Ksn[(srow + i * 32) * 72 + scol] = kr[i];
            #pragma unroll
            for (int i = 0; i < 2; i++) *(f32x4*)&Vsn[(srow + i * 32) * 72 + scol] = vr[i];
            cur ^= 1;
        }
    }

    // ---- epilogue: both kh halves to LDS; all 4 waves combine + write ----
    __syncthreads();                                  // loop LDS reads done; reuse shmem
    float (*Cb)[32][66] = (float (*)[32][66])&shmem[0][0];  // [kh*2+qh][32][66] = 33792 B
    #pragma unroll
    for (int nq = 0; nq < 2; nq++) {
        li[nq] += __shfl_xor(li[nq], 16);
        li[nq] += __shfl_xor(li[nq], 32);
    }
    if (lane < 16) {
        Lbuf[kh][qh * 32 + lane]      = li[0];
        Lbuf[kh][qh * 32 + 16 + lane] = li[1];
    }
    #pragma unroll
    for (int nq = 0; nq < 2; nq++)
        #pragma unroll
        for (int nh = 0; nh < 4; nh++)
            #pragma unroll
            for (int rg = 0; rg < 4; rg++)
                Cb[kh * 2 + qh][nq * 16 + quad * 4 + rg][nh * 16 + l15] = o[nq][nh][rg];
    __syncthreads();

    // 256 threads x (1 row, 16 cols): row = tid>>2, cols (tid&3)*16..+15
    int row = tid >> 2, cg = (tid & 3) * 16;
    int qh_r = row >> 5, ql_r = row & 31;
    size_t gout = ((size_t)b * Tn + Q0 + row) * Hn + cg;
    if (nch == 1) {
        float inv = 1.0f / (Lbuf[0][row] + Lbuf[1][row]);
        #pragma unroll
        for (int i = 0; i < 16; i++)
            Out[gout + i] = (Cb[qh_r][ql_r][cg + i] + Cb[2 + qh_r][ql_r][cg + i]) * inv;
    } else {
        #pragma unroll
        for (int i = 0; i < 16; i++)
            atomicAdd(&Out[gout + i], Cb[qh_r][ql_r][cg + i] + Cb[2 + qh_r][ql_r][cg + i]);
        if (tid < 64)
            atomicAdd(&Lsum[(b << 12) + Q0 + tid], Lbuf[0][tid] + Lbuf[1][tid]);
        __threadfence_block();   // s_waitcnt only: this block's atomics issued to LLC
        __syncthreads();
        if (tid == 0)
            lastflag = (atomicAdd(&cnt[b * 64 + qt], 1) == nch - 1);
        __syncthreads();
        if (lastflag) {          // all chunks' atomics at LLC; lines only ever LLC-touched
            __threadfence_block();
            size_t gbase = ((size_t)b * Tn + Q0) * Hn;
            #pragma unroll
            for (int i = 0; i < 4; i++) {
                int idx4 = tid + i * 256;            // 1024 f32x4 = 64 q x 64 h
                int q = idx4 >> 4;
                float inv = 1.0f / Lsum[(b << 12) + Q0 + q];
                f32x4 v = *(f32x4*)&Out[gbase + (size_t)idx4 * 4];
                v[0] *= inv; v[1] *= inv; v[2] *= inv; v[3] *= inv;
                *(f32x4*)&Out[gbase + (size_t)idx4 * 4] = v;
            }
        }
    }
}

extern "C" void kernel_launch(void* const* d_in, const int* in_sizes, int n_in,
                              void* d_out, int out_size, void* d_ws, size_t ws_size,
                              hipStream_t stream) {
    const float* X  = (const float*)d_in[0];
    const float* Wq = (const float*)d_in[1];
    const float* Wk = (const float*)d_in[2];
    const float* Wv = (const float*)d_in[3];
    float* out = (float*)d_out;

    char* ws = (char*)d_ws;
    size_t szQ = (size_t)Bn * Tn * Hn * sizeof(unsigned short);  // 4 MiB
    unsigned short* Qp  = (unsigned short*)(ws);
    unsigned short* Kp  = (unsigned short*)(ws + szQ);
    unsigned short* VTp = (unsigned short*)(ws + 2 * szQ);
    float*          Ls  = (float*)(ws + 3 * szQ);                // 128 KiB (8*4096 f32)
    int*            Ct  = (int*)(ws + 3 * szQ + (128 << 10));    // 2 KiB

    qkv<<<Bn * Tn / 64, 256, 0, stream>>>(X, Wq, Wk, Wv, Qp, Kp, VTp, out, Ls, Ct);
    attn<<<1280, 256, 0, stream>>>(Qp, Kp, VTp, out, Ls, Ct);
}

// Round 14
// 135.799 us; speedup vs baseline: 2.3254x; 2.3254x over previous
//
#include <hip/hip_runtime.h>
#include <hip/hip_bf16.h>

// Causal attention head. B=8, T=4096, D_EMBED=128, HEAD=64. f32 wire, bf16 MFMA.
// Two dispatches: qkv (inlined vectorized W-transpose + zero-init) and attn
// (balanced split-k, LDS double-buffer w/ 1 barrier/iter, lane-coalesced LLC-atomic
// combine, last-block normalize).
typedef __attribute__((ext_vector_type(8))) short bf16x8;
typedef __attribute__((ext_vector_type(4))) short short4v;
typedef __attribute__((ext_vector_type(4))) float f32x4;

#define MFMA16(a, b, c) __builtin_amdgcn_mfma_f32_16x16x32_bf16((a), (b), (c), 0, 0, 0)

// K=16 MFMA: P's S^T C-layout == its A-frag layout -> PV straight from registers.
// Host pass lacks the builtin; stub branch never executes on device.
__device__ inline f32x4 mfmax16(short4v a, short4v b, f32x4 c) {
#if __has_builtin(__builtin_amdgcn_mfma_f32_16x16x16bf16_1k)
    return __builtin_amdgcn_mfma_f32_16x16x16bf16_1k(a, b, c, 0, 0, 0);
#else
    return c;   // host-pass stub only
#endif
}

constexpr int Bn = 8, Tn = 4096, Dn = 128, Hn = 64;

__device__ inline unsigned short f2b(float f) {
    union { float f; unsigned u; } v; v.f = f;
    unsigned r = v.u + 0x7fff + ((v.u >> 16) & 1);   // RNE, inputs finite
    return (unsigned short)(r >> 16);
}
#if __has_builtin(__builtin_amdgcn_cvt_pk_bf16_f32)
typedef __attribute__((ext_vector_type(2))) __bf16 bf16x2_t;
__device__ inline unsigned pk2(float a, float b) {
    union { bf16x2_t v; unsigned u; } c;
    c.v = __builtin_amdgcn_cvt_pk_bf16_f32(a, b);
    return c.u;
}
#else
__device__ inline unsigned pk2(float a, float b) {
    return (unsigned)f2b(a) | ((unsigned)f2b(b) << 16);
}
#endif
__device__ inline short4v pk4(float a, float b, float c, float d) {
    union { unsigned u[2]; short4v s; } r;
    r.u[0] = pk2(a, b); r.u[1] = pk2(c, d);
    return r.s;
}

// ---- Kernel 1: QKV projection; inlined vectorized W transpose; zero-inits. ----
__global__ __launch_bounds__(256) void qkv(const float* __restrict__ X,
                                           const float* __restrict__ Wq,
                                           const float* __restrict__ Wk,
                                           const float* __restrict__ Wv,
                                           unsigned short* __restrict__ Qp,
                                           unsigned short* __restrict__ Kp,
                                           unsigned short* __restrict__ VTp,
                                           float* __restrict__ Out,
                                           float* __restrict__ Lsum,
                                           int* __restrict__ cnt) {
    __shared__ unsigned short xt[64 * 136];   // X tile bf16
    __shared__ unsigned short wt[64 * 136];   // W^T tile bf16 (one mat at a time)
    __shared__ unsigned short ot[64 * 72];    // output staging
    int tid = threadIdx.x, w = tid >> 6, lane = tid & 63, quad = lane >> 4, l15 = lane & 15;
    int g = blockIdx.x;
    int m0 = g * 64;
    int b = m0 >> 12, tloc = m0 & (Tn - 1);
    const float kLog2Scale = 0.12751879523175464f;  // (1/sqrt(128)) * log2(e)

    // zero-init: Out (this block's 4096 f32), Lsum slice, counters
    #pragma unroll
    for (int i = 0; i < 4; i++)
        *(f32x4*)&Out[(size_t)g * 4096 + (size_t)(tid + i * 256) * 4] = (f32x4){0.f, 0.f, 0.f, 0.f};
    if (tid < 64) Lsum[g * 64 + tid] = 0.f;
    if (g == 0) { cnt[tid] = 0; cnt[tid + 256] = 0; }

    // stage X tile (coalesced f32x4 -> bf16)
    #pragma unroll
    for (int c = 0; c < 8; c++) {
        int e = tid * 4 + c * 1024;
        int row = e >> 7, col = e & 127;
        f32x4 v = *(const f32x4*)&X[(size_t)(m0 + row) * Dn + col];
        *(short4v*)&xt[row * 136 + col] = pk4(v[0], v[1], v[2], v[3]);
    }
    __syncthreads();

    bf16x8 a[4];
    #pragma unroll
    for (int kt = 0; kt < 4; kt++)
        a[kt] = *(const bf16x8*)&xt[(w * 16 + l15) * 136 + kt * 32 + quad * 8];

    for (int mat = 0; mat < 3; mat++) {
        const float* W = (mat == 0) ? Wq : (mat == 1) ? Wk : Wv;
        __syncthreads();   // prior mat's wt frag reads + ot copy-out done
        // vectorized transpose: W[k][n] f32 -> wt[n][k] bf16, b64 LDS writes
        #pragma unroll
        for (int p = 0; p < 2; p++) {
            int kb = (tid >> 4) * 4 + p * 64;     // 0..124 step 4
            int n4 = (tid & 15) * 4;
            f32x4 wv0 = *(const f32x4*)&W[(kb + 0) * Hn + n4];
            f32x4 wv1 = *(const f32x4*)&W[(kb + 1) * Hn + n4];
            f32x4 wv2 = *(const f32x4*)&W[(kb + 2) * Hn + n4];
            f32x4 wv3 = *(const f32x4*)&W[(kb + 3) * Hn + n4];
            #pragma unroll
            for (int n = 0; n < 4; n++)
                *(short4v*)&wt[(n4 + n) * 136 + kb] = pk4(wv0[n], wv1[n], wv2[n], wv3[n]);
        }
        __syncthreads();

        f32x4 acc[4];
        #pragma unroll
        for (int nt = 0; nt < 4; nt++) {
            acc[nt] = (f32x4){0.f, 0.f, 0.f, 0.f};
            const unsigned short* wtm = &wt[(nt * 16 + l15) * 136 + quad * 8];
            #pragma unroll
            for (int kt = 0; kt < 4; kt++)
                acc[nt] = MFMA16(a[kt], *(const bf16x8*)&wtm[kt * 32], acc[nt]);
        }
        __syncthreads();
        if (mat < 2) {
            float sc = (mat == 0) ? kLog2Scale : 1.0f;   // fold softmax scale into Q
            #pragma unroll
            for (int nt = 0; nt < 4; nt++)
                #pragma unroll
                for (int rg = 0; rg < 4; rg++)
                    ot[(w * 16 + quad * 4 + rg) * 72 + nt * 16 + l15] = f2b(acc[nt][rg] * sc);
        } else {
            #pragma unroll
            for (int nt = 0; nt < 4; nt++)
                *(short4v*)&ot[(nt * 16 + l15) * 72 + w * 16 + quad * 4] =
                    pk4(acc[nt][0], acc[nt][1], acc[nt][2], acc[nt][3]);
        }
        __syncthreads();
        if (mat < 2) {
            unsigned short* O = mat ? Kp : Qp;
            #pragma unroll
            for (int i = 0; i < 2; i++) {
                int row = (tid >> 3) + 32 * i, ch8 = tid & 7;
                *(bf16x8*)&O[(size_t)(m0 + row) * Hn + ch8 * 8] = *(const bf16x8*)&ot[row * 72 + ch8 * 8];
            }
        } else {
            #pragma unroll
            for (int i = 0; i < 2; i++) {
                int h = (tid >> 3) + 32 * i, ch8 = tid & 7;
                *(bf16x8*)&VTp[((size_t)(b * Hn + h)) * Tn + tloc + ch8 * 8] = *(const bf16x8*)&ot[h * 72 + ch8 * 8];
            }
        }
    }
}

// ---- Kernel 2: balanced split-k flash attention; LDS double-buffer (1 barrier
// per iteration); lane-coalesced atomic combine; last-block normalize. ----
__global__ __launch_bounds__(256) void attn(const unsigned short* __restrict__ Qp,
                                            const unsigned short* __restrict__ Kp,
                                            const unsigned short* __restrict__ VTp,
                                            float* __restrict__ Out,
                                            float* __restrict__ Lsum,
                                            int* __restrict__ cnt) {
    __shared__ __align__(16) char shmem[2][18432];   // dbuf: Ks[64][72] + Vs[64][72] each
    __shared__ float Lbuf[2][64];
    __shared__ int lastflag;

    int idx = blockIdx.x;
    int b = idx & 7;
    int c = 159 - (idx >> 3);                        // big chunks dispatch first
    int qt, ch, nch;
    if (c < 16)      { qt = c;                 ch = 0;          nch = 1; }
    else if (c < 48) { int t = c - 16; qt = 16 + (t >> 1); ch = t & 1;      nch = 2; }
    else if (c < 96) { int t = c - 48; int q3 = t / 3; qt = 32 + q3; ch = t - 3 * q3; nch = 3; }
    else             { int t = c - 96; qt = 48 + (t >> 2); ch = t & 3;      nch = 4; }
    int k0 = ch * 16, k1 = min(qt, k0 + 15);

    int tid = threadIdx.x, w = tid >> 6, lane = tid & 63, quad = lane >> 4, l15 = lane & 15;
    int qh = w & 1, kh = w >> 1;
    int Q0 = qt * 64;
    const unsigned short* Kb = Kp + (size_t)b * Tn * Hn;
    const unsigned short* Vb = VTp + (size_t)b * Hn * Tn;

    int srow = tid >> 3, scol = (tid & 7) * 8;       // staging: 2 f32x4/thread/tile
    const f32x4* Ksrc = (const f32x4*)Kb;

    // tile k0 -> regs -> buf0 (loop-top barrier makes it visible)
    f32x4 kr[2], vr[2];
    #pragma unroll
    for (int i = 0; i < 2; i++) kr[i] = Ksrc[k0 * 512 + tid + i * 256];
    #pragma unroll
    for (int i = 0; i < 2; i++) vr[i] = *(const f32x4*)&Vb[(size_t)(srow + i * 32) * Tn + k0 * 64 + scol];
    {
        unsigned short* Ks0 = (unsigned short*)&shmem[0][0];
        unsigned short* Vs0 = Ks0 + 64 * 72;
        #pragma unroll
        for (int i = 0; i < 2; i++) *(f32x4*)&Ks0[(srow + i * 32) * 72 + scol] = kr[i];
        #pragma unroll
        for (int i = 0; i < 2; i++) *(f32x4*)&Vs0[(srow + i * 32) * 72 + scol] = vr[i];
    }

    bf16x8 qf[2][2];
    {
        const unsigned short* Qb = Qp + ((size_t)b * Tn + Q0 + qh * 32) * Hn;
        #pragma unroll
        for (int nq = 0; nq < 2; nq++)
            #pragma unroll
            for (int hc = 0; hc < 2; hc++)
                qf[nq][hc] = *(const bf16x8*)&Qb[(nq * 16 + l15) * Hn + hc * 32 + quad * 8];
    }

    f32x4 o[2][4];
    #pragma unroll
    for (int nq = 0; nq < 2; nq++)
        #pragma unroll
        for (int nh = 0; nh < 4; nh++) o[nq][nh] = (f32x4){0.f, 0.f, 0.f, 0.f};
    float li[2] = {0.f, 0.f};

    int cur = 0;
    for (int kt = k0; kt <= k1; kt++) {
        __syncthreads();   // buf[cur] writes visible; prior reads of buf[cur^1] done
        bool pref = (kt < k1);
        if (pref) {        // issue next tile's loads; latency overlaps compute
            #pragma unroll
            for (int i = 0; i < 2; i++) kr[i] = Ksrc[(kt + 1) * 512 + tid + i * 256];
            #pragma unroll
            for (int i = 0; i < 2; i++)
                vr[i] = *(const f32x4*)&Vb[(size_t)(srow + i * 32) * Tn + (kt + 1) * 64 + scol];
        }
        unsigned short* Ks = (unsigned short*)&shmem[cur][0];
        unsigned short* Vs = Ks + 64 * 72;

        bf16x8 kf[2][2];
        #pragma unroll
        for (int mt = 0; mt < 2; mt++)
            #pragma unroll
            for (int hc = 0; hc < 2; hc++)
                kf[mt][hc] = *(const bf16x8*)&Ks[(kh * 32 + mt * 16 + l15) * 72 + hc * 32 + quad * 8];

        // S^T tiles: rows k' = mt*16+quad*4+rg, cols q = nq*16+l15 (log2-scaled)
        f32x4 s[2][2];
        #pragma unroll
        for (int mt = 0; mt < 2; mt++)
            #pragma unroll
            for (int nq = 0; nq < 2; nq++) {
                f32x4 acc = {0.f, 0.f, 0.f, 0.f};
                acc = MFMA16(kf[mt][0], qf[nq][0], acc);
                acc = MFMA16(kf[mt][1], qf[nq][1], acc);
                s[mt][nq] = acc;
            }

        bool diag = (kt == qt);
        int kbase = kt * 64 + kh * 32 + quad * 4;
        int qbase = Q0 + qh * 32 + l15;

        short4v vB[2][4];
        #pragma unroll
        for (int mt = 0; mt < 2; mt++)
            #pragma unroll
            for (int nh = 0; nh < 4; nh++)
                vB[mt][nh] = *(const short4v*)&Vs[(nh * 16 + l15) * 72 + kh * 32 + mt * 16 + quad * 4];
        short4v pkv[2][2];
        #pragma unroll
        for (int mt = 0; mt < 2; mt++) {
            #pragma unroll
            for (int nq = 0; nq < 2; nq++) {
                float p[4];
                #pragma unroll
                for (int rg = 0; rg < 4; rg++) {
                    float pe = __builtin_amdgcn_exp2f(s[mt][nq][rg]);
                    if (diag && (kbase + mt * 16 + rg > qbase + nq * 16)) pe = 0.f;
                    li[nq] += pe;
                    p[rg] = pe;
                }
                pkv[mt][nq] = pk4(p[0], p[1], p[2], p[3]);
            }
        }
        #pragma unroll
        for (int mt = 0; mt < 2; mt++)
            #pragma unroll
            for (int nq = 0; nq < 2; nq++)
                #pragma unroll
                for (int nh = 0; nh < 4; nh++)
                    o[nq][nh] = mfmax16(pkv[mt][nq], vB[mt][nh], o[nq][nh]);

        if (pref) {        // stage tile kt+1 into the alternate buffer
            unsigned short* Ksn = (unsigned short*)&shmem[cur ^ 1][0];
            unsigned short* Vsn = Ksn + 64 * 72;
            #pragma unroll
            for (int i = 0; i < 2; i++) *(f32x4*)&Ksn[(srow + i * 32) * 72 + scol] = kr[i];
            #pragma unroll
            for (int i = 0; i < 2; i++) *(f32x4*)&Vsn[(srow + i * 32) * 72 + scol] = vr[i];
            cur ^= 1;
        }
    }

    // ---- epilogue: both kh halves to LDS; lane-coalesced combine + write ----
    __syncthreads();                                  // loop LDS reads done; reuse shmem
    float (*Cb)[32][66] = (float (*)[32][66])&shmem[0][0];  // [kh*2+qh][32][66] = 33792 B
    #pragma unroll
    for (int nq = 0; nq < 2; nq++) {
        li[nq] += __shfl_xor(li[nq], 16);
        li[nq] += __shfl_xor(li[nq], 32);
    }
    if (lane < 16) {
        Lbuf[kh][qh * 32 + lane]      = li[0];
        Lbuf[kh][qh * 32 + 16 + lane] = li[1];
    }
    #pragma unroll
    for (int nq = 0; nq < 2; nq++)
        #pragma unroll
        for (int nh = 0; nh < 4; nh++)
            #pragma unroll
            for (int rg = 0; rg < 4; rg++)
                Cb[kh * 2 + qh][nq * 16 + quad * 4 + rg][nh * 16 + l15] = o[nq][nh][rg];
    __syncthreads();

    if (nch == 1) {
        // vectorized, lane-coalesced: per wave-instr 64 lanes x 16 B contiguous
        #pragma unroll
        for (int i = 0; i < 4; i++) {
            int idx4 = i * 256 + tid;                 // f32x4 units, 1024 total
            int q = idx4 >> 4, c4 = (idx4 & 15) * 4;
            int qh_r = q >> 5, ql_r = q & 31;
            float inv = 1.0f / (Lbuf[0][q] + Lbuf[1][q]);
            f32x4 v;
            #pragma unroll
            for (int j = 0; j < 4; j++)
                v[j] = (Cb[qh_r][ql_r][c4 + j] + Cb[2 + qh_r][ql_r][c4 + j]) * inv;
            *(f32x4*)&Out[((size_t)b * Tn + Q0 + q) * Hn + c4] = v;
        }
    } else {
        // lane-coalesced atomics: per wave-instr one row x 64 consecutive floats
        #pragma unroll
        for (int i = 0; i < 16; i++) {
            int q = i * 4 + w, col = lane;
            int qh_r = q >> 5, ql_r = q & 31;
            atomicAdd(&Out[((size_t)b * Tn + Q0 + q) * Hn + col],
                      Cb[qh_r][ql_r][col] + Cb[2 + qh_r][ql_r][col]);
        }
        if (tid < 64)
            atomicAdd(&Lsum[(b << 12) + Q0 + tid], Lbuf[0][tid] + Lbuf[1][tid]);
        __threadfence_block();   // s_waitcnt only: this block's atomics issued to LLC
        __syncthreads();
        if (tid == 0)
            lastflag = (atomicAdd(&cnt[b * 64 + qt], 1) == nch - 1);
        __syncthreads();
        if (lastflag) {          // all chunks' atomics at LLC; lines only ever LLC-touched
            __threadfence_block();
            size_t gbase = ((size_t)b * Tn + Q0) * Hn;
            #pragma unroll
            for (int i = 0; i < 4; i++) {
                int idx4 = tid + i * 256;            // 1024 f32x4 = 64 q x 64 h
                int q = idx4 >> 4;
                float inv = 1.0f / Lsum[(b << 12) + Q0 + q];
                f32x4 v = *(f32x4*)&Out[gbase + (size_t)idx4 * 4];
                v[0] *= inv; v[1] *= inv; v[2] *= inv; v[3] *= inv;
                *(f32x4*)&Out[gbase + (size_t)idx4 * 4] = v;
            }
        }
    }
}

extern "C" void kernel_launch(void* const* d_in, const int* in_sizes, int n_in,
                              void* d_out, int out_size, void* d_ws, size_t ws_size,
                              hipStream_t stream) {
    const float* X  = (const float*)d_in[0];
    const float* Wq = (const float*)d_in[1];
    const float* Wk = (const float*)d_in[2];
    const float* Wv = (const float*)d_in[3];
    float* out = (float*)d_out;

    char* ws = (char*)d_ws;
    size_t szQ = (size_t)Bn * Tn * Hn * sizeof(unsigned short);  // 4 MiB
    unsigned short* Qp  = (unsigned short*)(ws);
    unsigned short* Kp  = (unsigned short*)(ws + szQ);
    unsigned short* VTp = (unsigned short*)(ws + 2 * szQ);
    float*          Ls  = (float*)(ws + 3 * szQ);                // 128 KiB (8*4096 f32)
    int*            Ct  = (int*)(ws + 3 * szQ + (128 << 10));    // 2 KiB

    qkv<<<Bn * Tn / 64, 256, 0, stream>>>(X, Wq, Wk, Wv, Qp, Kp, VTp, out, Ls, Ct);
    attn<<<1280, 256, 0, stream>>>(Qp, Kp, VTp, out, Ls, Ct);
}